// Round 16
// baseline (37.422 us; speedup 1.0000x reference)
//
#include <hip/hip_runtime.h>
#include <math.h>

// MultiHeadAttentionQuantum: analytic collapse of the 8-qubit circuit.
//   angles[t][n] = dot(x[t], w_q[n]) + q_params[n] ; c = cos(angles)
//   z[0] = c1..c7 ; z[w>=1] = c0..cw  (Heisenberg CNOT-ring push-through)
//   out[t][e] = sum_n z[n] * w_out[e][n]
//
// R16: occupancy proven irrelevant (15-54% -> same time). Remaining lever:
// amortize per-block fixed costs. Grid 512 (2 blocks/CU, balanced, no tail),
// each block runs 4 PIPELINED iterations over 16-token groups: weights
// staged ONCE per 64 tokens (staging L2 traffic 98->25 MB), next group's
// x-loads issued between current dot and finish (latency under ~1500cy of
// compute). R15 proved this register shape fits 128 VGPR spill-free.
// Everything else = R13 (best, 36.1us): fp32 weights in 48KB LDS, caching
// x loads, plain stores, circuit8, bounds(256,4).

using f32x4 = __attribute__((ext_vector_type(4))) float;

constexpr int E  = 768;
constexpr int NW = 8;
constexpr int BLOCK = 256;                      // 4 waves
constexpr int TOKENS = 16 * 2048;               // 32768
constexpr int TOK_PER_WAVE  = 4;
constexpr int TOK_PER_BLOCK = TOK_PER_WAVE * 4; // 16 per iteration
constexpr int GRID  = 512;                      // 2 blocks/CU, balanced
constexpr int ITERS = TOKENS / (GRID * TOK_PER_BLOCK);  // 4

__device__ __forceinline__ float dot12(const f32x4& a0, const f32x4& a1, const f32x4& a2,
                                       const f32x4& b0, const f32x4& b1, const f32x4& b2) {
    return a0.x*b0.x + a0.y*b0.y + a0.z*b0.z + a0.w*b0.w
         + a1.x*b1.x + a1.y*b1.y + a1.z*b1.z + a1.w*b1.w
         + a2.x*b2.x + a2.y*b2.y + a2.z*b2.z + a2.w*b2.w;
}

// Wave-wide reduce of zf[0..7] + cos + CNOT-ring prefix products.
// Numerically verified R4-R15 (absmax 0.0078).
__device__ __forceinline__ void circuit8(const float zf[NW], int lane, float qpl,
                                         float z[NW]) {
    float v4[4];
    #pragma unroll
    for (int i = 0; i < 4; ++i) {
        float a = zf[2*i], b = zf[2*i+1];
        float keep = (lane & 1) ? b : a;
        float send = (lane & 1) ? a : b;
        v4[i] = keep + __shfl_xor(send, 1, 64);
    }
    float v2[2];
    #pragma unroll
    for (int i = 0; i < 2; ++i) {
        float a = v4[2*i], b = v4[2*i+1];
        float keep = (lane & 2) ? b : a;
        float send = (lane & 2) ? a : b;
        v2[i] = keep + __shfl_xor(send, 2, 64);
    }
    float a = v2[0], b = v2[1];
    float keep = (lane & 4) ? b : a;
    float send = (lane & 4) ? a : b;
    float v = keep + __shfl_xor(send, 4, 64);
    v += __shfl_xor(v, 8, 64);
    v += __shfl_xor(v, 16, 64);
    v += __shfl_xor(v, 32, 64);
    float c = __cosf(v + qpl);               // one cos per token (wire lane&7)
    float cx = __shfl_xor(c, 1, 64);
    float e0 = (lane & 1) ? cx : c;
    float e1 = (lane & 1) ? c : cx;
    float e0x = __shfl_xor(e0, 2, 64), e1x = __shfl_xor(e1, 2, 64);
    float f0 = (lane & 2) ? e0x : e0;
    float f1 = (lane & 2) ? e1x : e1;
    float f2 = (lane & 2) ? e0  : e0x;
    float f3 = (lane & 2) ? e1  : e1x;
    float f0x = __shfl_xor(f0, 4, 64), f1x = __shfl_xor(f1, 4, 64);
    float f2x = __shfl_xor(f2, 4, 64), f3x = __shfl_xor(f3, 4, 64);
    float c0 = (lane & 4) ? f0x : f0;
    float c1 = (lane & 4) ? f1x : f1;
    float c2 = (lane & 4) ? f2x : f2;
    float c3 = (lane & 4) ? f3x : f3;
    float c4 = (lane & 4) ? f0  : f0x;
    float c5 = (lane & 4) ? f1  : f1x;
    float c6 = (lane & 4) ? f2  : f2x;
    float c7 = (lane & 4) ? f3  : f3x;
    float p1 = c0*c1, p2 = p1*c2, p3 = p2*c3, p4 = p3*c4;
    float p5 = p4*c5, p6 = p5*c6, p7 = p6*c7;
    float s  = c1*c2*c3*c4*c5*c6*c7;
    z[0] = s;  z[1] = p1; z[2] = p2; z[3] = p3;
    z[4] = p4; z[5] = p5; z[6] = p6; z[7] = p7;
}

__device__ __forceinline__ void load_x4(const float* __restrict__ x, int t0, int lane,
                                        f32x4 xv[TOK_PER_WAVE][3]) {
    #pragma unroll
    for (int tt = 0; tt < TOK_PER_WAVE; ++tt) {
        const f32x4* xp = reinterpret_cast<const f32x4*>(x + (size_t)(t0 + tt) * E);
        #pragma unroll
        for (int k = 0; k < 3; ++k)
            xv[tt][k] = xp[lane + k * 64];
    }
}

__device__ __forceinline__ void dot4(const f32x4 xv[TOK_PER_WAVE][3],
                                     const float (*wq)[E], int col,
                                     float zf[TOK_PER_WAVE][NW]) {
    #pragma unroll
    for (int n = 0; n < NW; ++n) {
        const f32x4 w0 = *reinterpret_cast<const f32x4*>(&wq[n][col]);
        const f32x4 w1 = *reinterpret_cast<const f32x4*>(&wq[n][col + 256]);
        const f32x4 w2 = *reinterpret_cast<const f32x4*>(&wq[n][col + 512]);
        #pragma unroll
        for (int tt = 0; tt < TOK_PER_WAVE; ++tt)
            zf[tt][n] = dot12(xv[tt][0], xv[tt][1], xv[tt][2], w0, w1, w2);
    }
}

__device__ __forceinline__ void finish4(float zf[TOK_PER_WAVE][NW],
                                        const float (*wt)[E],
                                        int t0, int lane, int col, float qpl,
                                        float* __restrict__ out) {
    float z[TOK_PER_WAVE][NW];
    #pragma unroll
    for (int tt = 0; tt < TOK_PER_WAVE; ++tt)
        circuit8(zf[tt], lane, qpl, z[tt]);

    #pragma unroll
    for (int k = 0; k < 3; ++k) {
        const int e0 = k * 256 + col;
        f32x4 wv[NW];
        #pragma unroll
        for (int n = 0; n < NW; ++n)
            wv[n] = *reinterpret_cast<const f32x4*>(&wt[n][e0]);
        #pragma unroll
        for (int tt = 0; tt < TOK_PER_WAVE; ++tt) {
            float ox = 0.f, oy = 0.f, oz = 0.f, ow = 0.f;
            #pragma unroll
            for (int n = 0; n < NW; ++n) {
                ox += z[tt][n] * wv[n].x;
                oy += z[tt][n] * wv[n].y;
                oz += z[tt][n] * wv[n].z;
                ow += z[tt][n] * wv[n].w;
            }
            f32x4 o; o.x = ox; o.y = oy; o.z = oz; o.w = ow;
            *reinterpret_cast<f32x4*>(out + (size_t)(t0 + tt) * E + e0) = o;
        }
    }
}

__global__ __launch_bounds__(BLOCK, 4)
void mhaq_kernel(const float* __restrict__ x,
                 const float* __restrict__ w_q,
                 const float* __restrict__ w_out,
                 const float* __restrict__ q_params,
                 float* __restrict__ out)
{
    __shared__ float wq_lds[NW][E];   // 24 KB, w_q as-is [n][e]
    __shared__ float wt_lds[NW][E];   // 24 KB, w_out transposed [n][e]

    const int tid  = threadIdx.x;
    const int wave = tid >> 6;
    const int lane = tid & 63;
    const int col  = lane * 4;
    // block owns 64 contiguous tokens; wave's slice within iteration it:
    //   t0(it) = tbase + it*16
    const int tbase = blockIdx.x * (TOK_PER_BLOCK * ITERS) + wave * TOK_PER_WAVE;

    // ---- iteration-0 x loads first: HBM latency overlaps staging ----
    f32x4 xbuf[2][TOK_PER_WAVE][3];
    load_x4(x, tbase, lane, xbuf[0]);

    // ---- stage weights ONCE per 64 tokens ----
    {
        const f32x4* src = reinterpret_cast<const f32x4*>(w_q);
        f32x4* dst = reinterpret_cast<f32x4*>(&wq_lds[0][0]);
        #pragma unroll
        for (int r = 0; r < (NW * E / 4) / BLOCK; ++r)
            dst[tid + r * BLOCK] = src[tid + r * BLOCK];
    }
    {
        const f32x4* src = reinterpret_cast<const f32x4*>(w_out);
        #pragma unroll
        for (int r = 0; r < (NW * E / 4) / BLOCK; ++r) {
            int idx = tid + r * BLOCK;       // f32x4 index into [768][8]
            f32x4 v = src[idx];
            int e  = idx >> 1;               // two f32x4 per e-row
            int n0 = (idx & 1) * 4;
            wt_lds[n0 + 0][e] = v.x;
            wt_lds[n0 + 1][e] = v.y;
            wt_lds[n0 + 2][e] = v.z;
            wt_lds[n0 + 3][e] = v.w;
        }
    }
    const float qpl = q_params[lane & 7];
    __syncthreads();

    // ---- 4 pipelined iterations: dot(cur) -> prefetch(next) -> finish(cur) ----
    #pragma unroll
    for (int it = 0; it < ITERS; ++it) {
        const int t0 = tbase + it * TOK_PER_BLOCK;
        float zf[TOK_PER_WAVE][NW];
        dot4(xbuf[it & 1], wq_lds, col, zf);           // xbuf[cur] now dead
        if (it + 1 < ITERS)
            load_x4(x, t0 + TOK_PER_BLOCK, lane, xbuf[(it + 1) & 1]);
        finish4(zf, wt_lds, t0, lane, col, qpl, out);  // covers next loads' latency
    }
}

extern "C" void kernel_launch(void* const* d_in, const int* in_sizes, int n_in,
                              void* d_out, int out_size, void* d_ws, size_t ws_size,
                              hipStream_t stream) {
    const float* x        = (const float*)d_in[0];
    const float* w_q      = (const float*)d_in[1];
    const float* w_out    = (const float*)d_in[2];
    const float* q_params = (const float*)d_in[3];
    float* out = (float*)d_out;

    hipLaunchKernelGGL(mhaq_kernel, dim3(GRID), dim3(BLOCK), 0, stream,
                       x, w_q, w_out, q_params, out);
}